// Round 6
// baseline (536.187 us; speedup 1.0000x reference)
//
#include <hip/hip_runtime.h>

// gcd(a,b)*W_gcd -> out[0..N), (a%p)*W_mod -> out[N..2N)
// a,b in [0,1e6), p in [1,1e6): all values < 2^20, nonnegative.
//
// GCD: Stein, 4-way interleaved, branch-divergence-free.
//   Inner step = 4 VALU inst: v_ffbl_b32 (-1 for 0; shift HW-masks amount
//   so 0 >> 31 == 0), v_lshrrev, v_sad_u32 (|a-b|), v_min_u32.
//   (0, g_odd) is a FIXED POINT of the step -> finished lanes iterate
//   harmlessly; wave-uniform __any exit check every 8 passes, full exec.
// MOD: exact fp32 (ints < 2^20): q = rint(a*rcp(p)) in {floor, floor+1},
//   r = fma(-q,p,a) exact, single fixup r += (r<0)?p:0.  Computed and
//   STORED BEFORE the GCD loop so the store overlaps GCD compute.
// PIPELINE: next group's a/b/p are loaded into registers BEFORE the GCD
//   loop of the current group -> load latency hides under ~500+ cycles of
//   GCD VALU work (R5 showed 33% idle = exposed load latency, since the
//   compiler can't hoist loads across the data-dependent while loop).

__device__ __forceinline__ unsigned ffbl(unsigned x) {
    unsigned r;
    asm("v_ffbl_b32 %0, %1" : "=v"(r) : "v"(x));   // -1 if x==0
    return r;
}

__global__ __launch_bounds__(256) void ntb_kernel(
    const int4* __restrict__ a4, const int4* __restrict__ b4,
    const int4* __restrict__ p4,
    const float* __restrict__ Wg, const float* __restrict__ Wm,
    float4* __restrict__ gcd_out, float4* __restrict__ mod_out, int n4)
{
    const float wg = Wg[0];
    const float wm = Wm[0];
    const int stride = gridDim.x * blockDim.x;

    int i = blockIdx.x * blockDim.x + threadIdx.x;
    if (i >= n4) return;

    int4 av = a4[i];
    int4 bv = b4[i];
    int4 pv = p4[i];

    while (true) {
        // ---- prefetch next group (wrap to 0 on last: in-bounds, discarded) ----
        const int inext = i + stride;
        const int idxn  = (inext < n4) ? inext : 0;
        const int4 av_n = a4[idxn];
        const int4 bv_n = b4[idxn];
        const int4 pv_n = p4[idxn];

        // ---- mod branch first: store early, overlap with GCD loop ----
        {
            const unsigned au[4] = {(unsigned)av.x, (unsigned)av.y, (unsigned)av.z, (unsigned)av.w};
            const unsigned pu[4] = {(unsigned)pv.x, (unsigned)pv.y, (unsigned)pv.z, (unsigned)pv.w};
            float mm[4];
            #pragma unroll
            for (int v = 0; v < 4; ++v) {
                const float af = (float)au[v];
                const float pf = (float)pu[v];
                const float q  = rintf(af * __builtin_amdgcn_rcpf(pf)); // {floor, floor+1}
                float r = fmaf(-q, pf, af);                             // exact, in (-p, p)
                r += (r < 0.0f) ? pf : 0.0f;
                mm[v] = r * wm;
            }
            float4 m;
            m.x = mm[0]; m.y = mm[1]; m.z = mm[2]; m.w = mm[3];
            mod_out[i] = m;
        }

        // ---- GCD ----
        unsigned A[4] = {(unsigned)av.x, (unsigned)av.y, (unsigned)av.z, (unsigned)av.w};
        unsigned B[4] = {(unsigned)bv.x, (unsigned)bv.y, (unsigned)bv.z, (unsigned)bv.w};
        unsigned S[4];
        #pragma unroll
        for (int v = 0; v < 4; ++v) {
            S[v] = ffbl(A[v] | B[v]);            // &31 folds into the final shift
            A[v] >>= (ffbl(A[v]) & 31u);         // A=0 -> stays 0
        }

        for (;;) {
            #pragma unroll
            for (int it = 0; it < 8; ++it) {
                #pragma unroll
                for (int v = 0; v < 4; ++v) {
                    const unsigned b  = B[v] >> (ffbl(B[v]) & 31u); // 0 -> 0
                    const unsigned nb = __usad(A[v], b, 0u);        // |A - b|
                    A[v] = min(A[v], b);
                    B[v] = nb;
                }
            }
            if (!__any((A[0] | A[1] | A[2] | A[3]) != 0u)) break;
        }

        float4 g;
        g.x = (float)((A[0] | B[0]) << (S[0] & 31u)) * wg;
        g.y = (float)((A[1] | B[1]) << (S[1] & 31u)) * wg;
        g.z = (float)((A[2] | B[2]) << (S[2] & 31u)) * wg;
        g.w = (float)((A[3] | B[3]) << (S[3] & 31u)) * wg;
        gcd_out[i] = g;

        if (inext >= n4) break;
        i = inext;
        av = av_n; bv = bv_n; pv = pv_n;
    }
}

extern "C" void kernel_launch(void* const* d_in, const int* in_sizes, int n_in,
                              void* d_out, int out_size, void* d_ws, size_t ws_size,
                              hipStream_t stream) {
    const int n  = in_sizes[0];   // 2^25
    const int n4 = n >> 2;

    const int4* a4 = (const int4*)d_in[0];
    const int4* b4 = (const int4*)d_in[1];
    const int4* p4 = (const int4*)d_in[2];
    const float* Wg = (const float*)d_in[3];
    const float* Wm = (const float*)d_in[4];

    float* out = (float*)d_out;
    float4* gcd_out = (float4*)out;        // first N floats
    float4* mod_out = (float4*)(out + n);  // second N floats

    const int block = 256;
    const int grid  = 4096;  // 8 groups/thread: 7/8 of loads hidden by prefetch

    ntb_kernel<<<grid, block, 0, stream>>>(a4, b4, p4, Wg, Wm, gcd_out, mod_out, n4);
}

// Round 7
// 532.847 us; speedup vs baseline: 1.0063x; 1.0063x over previous
//
#include <hip/hip_runtime.h>

// gcd(a,b)*W_gcd -> out[0..N), (a%p)*W_mod -> out[N..2N)
// a,b in [0,1e6), p in [1,1e6): all values < 2^20, nonnegative.
//
// GCD: Stein, 4-way interleaved, branch-divergence-free (R5 structure).
//   Inner step = 4 VALU inst: v_ffbl_b32 (-1 for 0; shifts HW-mask the
//   amount so 0>>31==0), v_lshrrev, v_sad_u32, v_min_u32. (0,g_odd) is a
//   fixed point -> finished lanes iterate harmlessly; wave-uniform __any
//   exit check every 8 passes, full exec mask.
// MOD: exact fp32 (ints < 2^20): q=rint(a*rcp(p)) in {floor,floor+1},
//   r=fma(-q,p,a) exact, single fixup.
// PIPELINE (the R6 fix): R6's C++ prefetch was SUNK by the compiler
//   (VGPR=20 proved the values weren't held). Now the 3 next-group loads
//   are asm volatile global_load_dwordx4 with "memory" clobber -> cannot
//   sink, stores cannot cross. Consumed after `s_waitcnt vmcnt(2)`:
//   exactly 2 vmem ops (the 2 output stores) issue after the 3 loads, and
//   vmcnt retires in FIFO order, so vmcnt(2) == "3 prefetch loads landed"
//   while stores stay in flight. sched_barrier(0) pins register uses
//   behind the wait (rule #18).

typedef int v4i __attribute__((ext_vector_type(4)));

__device__ __forceinline__ unsigned ffbl(unsigned x) {
    unsigned r;
    asm("v_ffbl_b32 %0, %1" : "=v"(r) : "v"(x));   // -1 if x==0
    return r;
}

__device__ __forceinline__ v4i prefetch16(const v4i* p) {
    v4i r;
    asm volatile("global_load_dwordx4 %0, %1, off"
                 : "=v"(r) : "v"(p) : "memory");
    return r;
}

__global__ __launch_bounds__(256) void ntb_kernel(
    const v4i* __restrict__ a4, const v4i* __restrict__ b4,
    const v4i* __restrict__ p4,
    const float* __restrict__ Wg, const float* __restrict__ Wm,
    float4* __restrict__ gcd_out, float4* __restrict__ mod_out, int n4)
{
    const float wg = Wg[0];
    const float wm = Wm[0];
    const int stride = gridDim.x * blockDim.x;

    int i = blockIdx.x * blockDim.x + threadIdx.x;
    if (i >= n4) return;

    v4i av = a4[i];          // first group: plain loads (compiler-waited)
    v4i bv = b4[i];
    v4i pv = p4[i];

    while (true) {
        // ---- un-sinkable prefetch of next group ----
        const int inext = i + stride;
        const int idxn  = (inext < n4) ? inext : 0;   // wrap: in-bounds, discarded
        const v4i av_n = prefetch16(a4 + idxn);
        const v4i bv_n = prefetch16(b4 + idxn);
        const v4i pv_n = prefetch16(p4 + idxn);

        // ---- mod branch (store overlaps the GCD loop) ----
        {
            float mm[4];
            #pragma unroll
            for (int v = 0; v < 4; ++v) {
                const float af = (float)(unsigned)av[v];
                const float pf = (float)(unsigned)pv[v];
                const float q  = rintf(af * __builtin_amdgcn_rcpf(pf)); // {floor,floor+1}
                float r = fmaf(-q, pf, af);                             // exact, in (-p,p)
                r += (r < 0.0f) ? pf : 0.0f;
                mm[v] = r * wm;
            }
            float4 m; m.x = mm[0]; m.y = mm[1]; m.z = mm[2]; m.w = mm[3];
            mod_out[i] = m;
        }

        // ---- GCD ----
        unsigned A[4], B[4], S[4];
        #pragma unroll
        for (int v = 0; v < 4; ++v) {
            A[v] = (unsigned)av[v];
            B[v] = (unsigned)bv[v];
            S[v] = ffbl(A[v] | B[v]);            // &31 folds into the final shift
            A[v] >>= (ffbl(A[v]) & 31u);         // A=0 -> stays 0
        }

        for (;;) {
            #pragma unroll
            for (int it = 0; it < 8; ++it) {
                #pragma unroll
                for (int v = 0; v < 4; ++v) {
                    const unsigned b  = B[v] >> (ffbl(B[v]) & 31u); // 0 -> 0
                    const unsigned nb = __usad(A[v], b, 0u);        // |A - b|
                    A[v] = min(A[v], b);
                    B[v] = nb;
                }
            }
            if (!__any((A[0] | A[1] | A[2] | A[3]) != 0u)) break;
        }

        float4 g;
        g.x = (float)((A[0] | B[0]) << (S[0] & 31u)) * wg;
        g.y = (float)((A[1] | B[1]) << (S[1] & 31u)) * wg;
        g.z = (float)((A[2] | B[2]) << (S[2] & 31u)) * wg;
        g.w = (float)((A[3] | B[3]) << (S[3] & 31u)) * wg;
        gcd_out[i] = g;

        if (inext >= n4) break;

        // ---- consume prefetch: 2 stores issued after the 3 loads ----
        asm volatile("s_waitcnt vmcnt(2)" ::: "memory");
        __builtin_amdgcn_sched_barrier(0);
        i = inext;
        av = av_n; bv = bv_n; pv = pv_n;
    }
}

extern "C" void kernel_launch(void* const* d_in, const int* in_sizes, int n_in,
                              void* d_out, int out_size, void* d_ws, size_t ws_size,
                              hipStream_t stream) {
    const int n  = in_sizes[0];   // 2^25
    const int n4 = n >> 2;

    const v4i* a4 = (const v4i*)d_in[0];
    const v4i* b4 = (const v4i*)d_in[1];
    const v4i* p4 = (const v4i*)d_in[2];
    const float* Wg = (const float*)d_in[3];
    const float* Wm = (const float*)d_in[4];

    float* out = (float*)d_out;
    float4* gcd_out = (float4*)out;        // first N floats
    float4* mod_out = (float4*)(out + n);  // second N floats

    const int block = 256;
    const int grid  = 4096;  // 8 groups/thread: 7/8 of loads prefetch-hidden

    ntb_kernel<<<grid, block, 0, stream>>>(a4, b4, p4, Wg, Wm, gcd_out, mod_out, n4);
}